// Round 8
// baseline (223.406 us; speedup 1.0000x reference)
//
#include <hip/hip_runtime.h>

#define NBLK 256
#define FPAD 16   // 64 B per flag slot

#define AG_LD(p)    __hip_atomic_load((p), __ATOMIC_RELAXED, __HIP_MEMORY_SCOPE_AGENT)
#define AG_ST(p, v) __hip_atomic_store((p), (v), __ATOMIC_RELAXED, __HIP_MEMORY_SCOPE_AGENT)

// Fan-out grid barrier (validated R5-R7). fence only after the transpose
// phase (kills stale poison lines); all later cross-block data moves via
// agent-scope relaxed atomics so each XCD's L2 stays warm with weights.
__device__ __forceinline__ void gridbar(int n, unsigned* flags, unsigned* rel,
                                        int bid, bool fence) {
    __syncthreads();
    if (threadIdx.x == 0)
        __hip_atomic_store(&flags[bid * FPAD], (unsigned)n, __ATOMIC_RELEASE,
                           __HIP_MEMORY_SCOPE_AGENT);
    if (bid == 0) {
        if (threadIdx.x < NBLK) {
            while ((int)__hip_atomic_load(&flags[threadIdx.x * FPAD],
                                          __ATOMIC_RELAXED,
                                          __HIP_MEMORY_SCOPE_AGENT) < n)
                __builtin_amdgcn_s_sleep(1);
        }
        __syncthreads();
        if (threadIdx.x < 16)
            __hip_atomic_store(&rel[(n * 16 + threadIdx.x) * FPAD], (unsigned)n,
                               __ATOMIC_RELEASE, __HIP_MEMORY_SCOPE_AGENT);
    } else {
        if (threadIdx.x == 0) {
            while ((int)__hip_atomic_load(&rel[(n * 16 + (bid & 15)) * FPAD],
                                          __ATOMIC_RELAXED,
                                          __HIP_MEMORY_SCOPE_AGENT) < n)
                __builtin_amdgcn_s_sleep(1);
        }
    }
    if (fence) __builtin_amdgcn_fence(__ATOMIC_ACQUIRE, "agent");
    __syncthreads();
}

// Packed weight layout: Wp[(k>>2)*1024 + c*4 + (k&3)]  (float4 per (kg,c))
// -> lane c loads one dwordx4 = 4 k-values, wave = 1KB contiguous.

// Per-batch softmax combine + sigmoid + U2 matvec + updB. Redundant/block.
// 1024 threads: c = tid&255, rq = tid>>8 (0..3).
__device__ __forceinline__ float phaseB(int i, int b, int c, int rq,
                                        const float* __restrict__ part,
                                        const float* __restrict__ WtB,
                                        const float* __restrict__ updB,
                                        float* sc, float* aggl) {
    float M = -1e30f, den = 0.f, num = 0.f;
    const int par = i & 1;
    #pragma unroll
    for (int j = rq * 4; j < rq * 4 + 4; ++j) {
        const float* pp = part + (size_t)(par * 256 + b * 16 + j) * 768;
        const float mj = AG_LD(pp + c);
        const float dj = AG_LD(pp + 256 + c);
        const float nj = AG_LD(pp + 512 + c);
        const float Mn = fmaxf(M, mj);
        const float s = __expf(M - Mn), e = __expf(mj - Mn);
        den = den * s + dj * e;
        num = num * s + nj * e;
        M = Mn;
    }
    sc[rq * 256 + c] = M;
    sc[1024 + rq * 256 + c] = den;
    sc[2048 + rq * 256 + c] = num;
    __syncthreads();
    if (rq == 0) {
        float Mx = sc[c];
        #pragma unroll
        for (int g = 1; g < 4; ++g) Mx = fmaxf(Mx, sc[g * 256 + c]);
        float dd = 0.f, nn = 0.f;
        #pragma unroll
        for (int g = 0; g < 4; ++g) {
            const float e = __expf(sc[g * 256 + c] - Mx);
            dd += sc[1024 + g * 256 + c] * e;
            nn += sc[2048 + g * 256 + c] * e;
        }
        aggl[c] = 1.f / (1.f + __expf(-(nn / dd)));
    }
    __syncthreads();
    // U2 matvec: 64 k (16 quads) per rq group, packed dwordx4 stream
    const float4* U2q = (const float4*)(WtB + (size_t)(9 + i) * 65536);
    float au = 0.f;
    float4 wa = U2q[(rq * 16) * 256 + c];
    #pragma unroll 4
    for (int kg = rq * 16; kg < rq * 16 + 16; ++kg) {
        float4 wb;
        if (kg < rq * 16 + 15) wb = U2q[(kg + 1) * 256 + c];
        const float4 ag = *(const float4*)&aggl[kg * 4];
        au += ag.x * wa.x + ag.y * wa.y + ag.z * wa.z + ag.w * wa.w;
        wa = wb;
    }
    __syncthreads();
    sc[rq * 256 + c] = au;
    __syncthreads();
    return sc[c] + sc[256 + c] + sc[512 + c] + sc[768 + c] + updB[i * 256 + c];
}

__global__ __launch_bounds__(1024, 4) void fused_k(
    const float* __restrict__ feat,   // [16][128][256]
    const float* __restrict__ mask,   // [16][128]
    const float* __restrict__ aggW,   // [3][256][256]
    const float* __restrict__ aggB,   // [3][256]
    const float* __restrict__ attnW,  // [3][256][512]
    const float* __restrict__ updW,   // [3][256][512]
    const float* __restrict__ updB,   // [3][256]
    float* __restrict__ WtB,          // 12 * 65536 packed k-quad layout
    float* __restrict__ part,         // 2 * 256 * 768
    unsigned* flags, unsigned* rel,
    float* __restrict__ out)
{
    __shared__ float ldsa[7424];  // hidl[2048] xl[2048] sc[3072] aggl[256]
    float* hidl = ldsa;
    float* xl   = ldsa + 2048;
    float* sc   = ldsa + 4096;
    float* aggl = ldsa + 7168;

    const int bid = blockIdx.x;
    const int tid = threadIdx.x;
    const int c  = tid & 255;
    const int rq = tid >> 8;                        // 0..3, wave-uniform
    const int b  = bid >> 4, jj = bid & 15;
    const int rbase = b * 128 + jj * 8 + rq * 2;    // thread's first row (of 2)

    // ---- P0: transpose+pack 12 weight mats (blocks 0..191)
    if (bid < 192) {
        float (*Tl)[65] = (float (*)[65])ldsa;      // 64x65 tile
        const int m = bid >> 4, t = bid & 15, tr = t >> 2, tc = t & 3;
        const float* src; int stride, off;
        if (m < 3)      { src = aggW  + (size_t)m * 65536;        stride = 256; off = 0;   }
        else if (m < 6) { src = attnW + (size_t)(m - 3) * 131072; stride = 512; off = 0;   }
        else if (m < 9) { src = updW  + (size_t)(m - 6) * 131072; stride = 512; off = 0;   }
        else            { src = updW  + (size_t)(m - 9) * 131072; stride = 512; off = 256; }
        float* dst = WtB + (size_t)m * 65536;
        {   // read 64x64 tile (rows=c, cols=k), one float4 per thread
            const int row = tid >> 4, q = (tid & 15) * 4;
            const float4 v = *(const float4*)(src + (size_t)(tr * 64 + row) * stride + off + tc * 64 + q);
            Tl[row][q + 0] = v.x; Tl[row][q + 1] = v.y;
            Tl[row][q + 2] = v.z; Tl[row][q + 3] = v.w;
        }
        __syncthreads();
        {   // write packed: quad (kg_l = tid>>6, cl = tid&63)
            const int kgl = tid >> 6, cl = tid & 63;
            float4 v;
            v.x = Tl[cl][kgl * 4 + 0]; v.y = Tl[cl][kgl * 4 + 1];
            v.z = Tl[cl][kgl * 4 + 2]; v.w = Tl[cl][kgl * 4 + 3];
            *(float4*)(dst + (size_t)(tc * 16 + kgl) * 1024 + (tr * 64 + cl) * 4) = v;
        }
    }
    gridbar(1, flags, rel, bid, true);   // fence: publish WtB, kill poison

    float xu0 = 0.f, xu1 = 0.f;
    float accU = 0.f;

    for (int i = 0; i < 3; ++i) {
        if (i > 0)
            accU = phaseB(i - 1, b, c, rq, part, WtB, updB, sc, aggl);

        // ---- build hid rows in LDS: hidl[r][k], r=0..7 local, k=c per lane
        if (i == 0) {
            #pragma unroll
            for (int r = 0; r < 2; ++r)
                hidl[(rq * 2 + r) * 256 + c] =
                    feat[(size_t)(rbase + r) * 256 + c] * mask[rbase + r];
        } else {
            const float xur[2] = {xu0, xu1};
            #pragma unroll
            for (int r = 0; r < 2; ++r)
                hidl[(rq * 2 + r) * 256 + c] = (xur[r] + accU) * mask[rbase + r];
        }
        __syncthreads();

        // ---- P1: x = hid @ aggW^T + aggB   (packed quad stream, 2 rows)
        {
            const float4* Wq = (const float4*)(WtB + (size_t)i * 65536);
            const float* h0 = &hidl[(rq * 2 + 0) * 256];
            const float* h1 = &hidl[(rq * 2 + 1) * 256];
            float a0 = 0.f, a1 = 0.f;
            float4 wa = Wq[c];
            #pragma unroll 4
            for (int kg = 0; kg < 64; ++kg) {
                float4 wb;
                if (kg < 63) wb = Wq[(kg + 1) * 256 + c];
                const float4 q0 = *(const float4*)&h0[kg * 4];
                const float4 q1 = *(const float4*)&h1[kg * 4];
                a0 += q0.x * wa.x + q0.y * wa.y + q0.z * wa.z + q0.w * wa.w;
                a1 += q1.x * wa.x + q1.y * wa.y + q1.z * wa.z + q1.w * wa.w;
                wa = wb;
            }
            const float bb = aggB[i * 256 + c];
            xl[(rq * 2 + 0) * 256 + c] = a0 + bb;
            xl[(rq * 2 + 1) * 256 + c] = a1 + bb;
        }
        __syncthreads();

        // ---- P2: p = x@W1^T, xU1 = x@U1^T   (two packed streams)
        float p0 = 0.f, p1 = 0.f;
        {
            const float4* W1q = (const float4*)(WtB + (size_t)(3 + i) * 65536);
            const float4* U1q = (const float4*)(WtB + (size_t)(6 + i) * 65536);
            const float* x0 = &xl[(rq * 2 + 0) * 256];
            const float* x1 = &xl[(rq * 2 + 1) * 256];
            float u0 = 0.f, u1 = 0.f;
            float4 wa = W1q[c], ua = U1q[c];
            #pragma unroll 4
            for (int kg = 0; kg < 64; ++kg) {
                float4 wb, ub;
                if (kg < 63) { wb = W1q[(kg + 1) * 256 + c]; ub = U1q[(kg + 1) * 256 + c]; }
                const float4 q0 = *(const float4*)&x0[kg * 4];
                const float4 q1 = *(const float4*)&x1[kg * 4];
                p0 += q0.x * wa.x + q0.y * wa.y + q0.z * wa.z + q0.w * wa.w;
                p1 += q1.x * wa.x + q1.y * wa.y + q1.z * wa.z + q1.w * wa.w;
                u0 += q0.x * ua.x + q0.y * ua.y + q0.z * ua.z + q0.w * ua.w;
                u1 += q1.x * ua.x + q1.y * ua.y + q1.z * ua.z + q1.w * ua.w;
                wa = wb; ua = ub;
            }
            xu0 = u0; xu1 = u1;
        }

        // ---- online-softmax partials over this thread's 2 rows
        {
            const float xv0 = xl[(rq * 2 + 0) * 256 + c];
            const float xv1 = xl[(rq * 2 + 1) * 256 + c];
            const float m2 = fmaxf(p0, p1);
            const float e0 = __expf(p0 - m2), e1 = __expf(p1 - m2);
            sc[rq * 256 + c] = m2;
            sc[1024 + rq * 256 + c] = e0 + e1;
            sc[2048 + rq * 256 + c] = e0 * xv0 + e1 * xv1;
        }
        __syncthreads();
        if (rq == 0) {
            float Mx = sc[c];
            #pragma unroll
            for (int g = 1; g < 4; ++g) Mx = fmaxf(Mx, sc[g * 256 + c]);
            float dd = 0.f, nn = 0.f;
            #pragma unroll
            for (int g = 0; g < 4; ++g) {
                const float e = __expf(sc[g * 256 + c] - Mx);
                dd += sc[1024 + g * 256 + c] * e;
                nn += sc[2048 + g * 256 + c] * e;
            }
            float* pb = part + (size_t)((i & 1) * 256 + bid) * 768;
            AG_ST(pb + c, Mx);
            AG_ST(pb + 256 + c, dd);
            AG_ST(pb + 512 + c, nn);
        }
        gridbar(i + 2, flags, rel, bid, false);   // no fence: L2 stays warm
    }

    // ---- final combine + epilogue: out = xU1 + accU
    accU = phaseB(2, b, c, rq, part, WtB, updB, sc, aggl);
    out[(size_t)(rbase + 0) * 256 + c] = xu0 + accU;
    out[(size_t)(rbase + 1) * 256 + c] = xu1 + accU;
}

extern "C" void kernel_launch(void* const* d_in, const int* in_sizes, int n_in,
                              void* d_out, int out_size, void* d_ws, size_t ws_size,
                              hipStream_t stream) {
    const float* feat  = (const float*)d_in[0];
    const float* mask  = (const float*)d_in[1];
    const float* aggW  = (const float*)d_in[2];
    const float* aggB  = (const float*)d_in[3];
    const float* attnW = (const float*)d_in[4];
    // d_in[5] = attnB: cancels in softmax (constant along the s axis)
    const float* updW  = (const float*)d_in[6];
    const float* updB  = (const float*)d_in[7];

    float* WtB  = (float*)d_ws;                        // 12 * 65536 floats
    float* part = WtB + 12 * 65536;                    // 2 * 256 * 768 floats
    unsigned* flags = (unsigned*)(part + 2 * 256 * 768);
    unsigned* rel   = flags + NBLK * FPAD;

    fused_k<<<NBLK, 1024, 0, stream>>>(
        feat, mask, aggW, aggB, attnW, updW, updB,
        WtB, part, flags, rel, (float*)d_out);
}

// Round 9
// 160.953 us; speedup vs baseline: 1.3880x; 1.3880x over previous
//
#include <hip/hip_runtime.h>

#define NBLK 256
#define FPAD 16   // 64 B per flag slot

typedef float v2f __attribute__((ext_vector_type(2)));

#define AG_LD(p)    __hip_atomic_load((p), __ATOMIC_RELAXED, __HIP_MEMORY_SCOPE_AGENT)
#define AG_ST(p, v) __hip_atomic_store((p), (v), __ATOMIC_RELAXED, __HIP_MEMORY_SCOPE_AGENT)

// Fan-out grid barrier (validated R5-R7). fence only after the transpose
// phase; later cross-block data moves via agent-scope relaxed atomics so
// each XCD's L2 stays warm with weights.
__device__ __forceinline__ void gridbar(int n, unsigned* flags, unsigned* rel,
                                        int bid, bool fence) {
    __syncthreads();
    if (threadIdx.x == 0)
        __hip_atomic_store(&flags[bid * FPAD], (unsigned)n, __ATOMIC_RELEASE,
                           __HIP_MEMORY_SCOPE_AGENT);
    if (bid == 0) {
        if (threadIdx.x < NBLK) {
            while ((int)__hip_atomic_load(&flags[threadIdx.x * FPAD],
                                          __ATOMIC_RELAXED,
                                          __HIP_MEMORY_SCOPE_AGENT) < n)
                __builtin_amdgcn_s_sleep(1);
        }
        __syncthreads();
        if (threadIdx.x < 16)
            __hip_atomic_store(&rel[(n * 16 + threadIdx.x) * FPAD], (unsigned)n,
                               __ATOMIC_RELEASE, __HIP_MEMORY_SCOPE_AGENT);
    } else {
        if (threadIdx.x == 0) {
            while ((int)__hip_atomic_load(&rel[(n * 16 + (bid & 15)) * FPAD],
                                          __ATOMIC_RELAXED,
                                          __HIP_MEMORY_SCOPE_AGENT) < n)
                __builtin_amdgcn_s_sleep(1);
        }
    }
    if (fence) __builtin_amdgcn_fence(__ATOMIC_ACQUIRE, "agent");
    __syncthreads();
}

// Packed weight layout: Wp[kg*1024 + c*4 + (k&3)] (float4 per (kg,c)):
// lane c loads dwordx4 = 4 k-values, wave = 1 KB contiguous.

// Per-batch softmax combine + sigmoid + U2 matvec (k-split by rq, packed
// prefetch) + updB. Redundant per block. 512 threads: c=tid&255, rq=tid>>8.
__device__ __forceinline__ float phaseB(int i, int b, int c, int rq,
                                        const float* __restrict__ part,
                                        const float* __restrict__ WtB,
                                        const float* __restrict__ updB,
                                        float* sc, float* aggl) {
    float M = -1e30f, den = 0.f, num = 0.f;
    const int par = i & 1;
    #pragma unroll
    for (int j = rq * 8; j < rq * 8 + 8; ++j) {
        const float* pp = part + (size_t)(par * 256 + b * 16 + j) * 768;
        const float mj = AG_LD(pp + c);
        const float dj = AG_LD(pp + 256 + c);
        const float nj = AG_LD(pp + 512 + c);
        const float Mn = fmaxf(M, mj);
        const float s = __expf(M - Mn), e = __expf(mj - Mn);
        den = den * s + dj * e;
        num = num * s + nj * e;
        M = Mn;
    }
    sc[rq * 256 + c] = M;
    sc[512 + rq * 256 + c] = den;
    sc[1024 + rq * 256 + c] = num;
    __syncthreads();
    if (rq == 0) {
        const float m0 = sc[c], m1 = sc[256 + c];
        const float Mx = fmaxf(m0, m1);
        const float s0 = __expf(m0 - Mx), s1 = __expf(m1 - Mx);
        const float dd = sc[512 + c] * s0 + sc[768 + c] * s1;
        const float nn = sc[1024 + c] * s0 + sc[1280 + c] * s1;
        aggl[c] = 1.f / (1.f + __expf(-(nn / dd)));
    }
    __syncthreads();
    // U2 matvec: 32 packed quads per rq group (k-split, 1x traffic)
    const float4* U2q = (const float4*)(WtB + (size_t)(9 + i) * 65536);
    const int kg0 = rq * 32;
    float4 buf[8];
    #pragma unroll
    for (int j = 0; j < 8; ++j) buf[j] = U2q[(size_t)(kg0 + j) * 256 + c];
    v2f au = {0.f, 0.f};
    #pragma unroll
    for (int ph = 0; ph < 4; ++ph) {
        #pragma unroll
        for (int j = 0; j < 8; ++j) {
            const float4 w = buf[j];
            if (ph < 3) buf[j] = U2q[(size_t)(kg0 + (ph + 1) * 8 + j) * 256 + c];
            const float4 ag = *(const float4*)&aggl[(kg0 + ph * 8 + j) * 4];
            au += (v2f){ag.x, ag.y} * (v2f){w.x, w.y};
            au += (v2f){ag.z, ag.w} * (v2f){w.z, w.w};
        }
    }
    __syncthreads();
    sc[rq * 256 + c] = au.x + au.y;
    __syncthreads();
    return sc[c] + sc[256 + c] + updB[i * 256 + c];
}

__global__ __launch_bounds__(512, 2) void fused_k(
    const float* __restrict__ feat,   // [16][128][256]
    const float* __restrict__ mask,   // [16][128]
    const float* __restrict__ aggW,   // [3][256][256]
    const float* __restrict__ aggB,   // [3][256]
    const float* __restrict__ attnW,  // [3][256][512]
    const float* __restrict__ updW,   // [3][256][512]
    const float* __restrict__ updB,   // [3][256]
    float* __restrict__ WtB,          // 12 * 65536 packed k-quad layout
    float* __restrict__ part,         // 2 * 256 * 768
    unsigned* flags, unsigned* rel,
    float* __restrict__ out)
{
    __shared__ float ldsa[6400];  // hidl[2048] xl[2048] sc[2048] aggl[256]
    float* hidl = ldsa;           // [row 0..7][k 0..255]
    float* xl   = ldsa + 2048;    // [row 0..7][k 0..255]
    float* sc   = ldsa + 4096;
    float* aggl = ldsa + 6144;

    const int bid = blockIdx.x;
    const int tid = threadIdx.x;
    const int c  = tid & 255;
    const int rq = tid >> 8;                  // 0..1, wave-uniform
    const int b  = bid >> 4, jj = bid & 15;
    const int row0 = b * 128 + jj * 8;        // block's first row

    // ---- P0: transpose+pack 12 weight mats (blocks 0..191)
    if (bid < 192) {
        float (*Tl)[65] = (float (*)[65])ldsa;
        const int m = bid >> 4, t = bid & 15, tr = t >> 2, tc = t & 3;
        const float* src; int stride, off;
        if (m < 3)      { src = aggW  + (size_t)m * 65536;        stride = 256; off = 0;   }
        else if (m < 6) { src = attnW + (size_t)(m - 3) * 131072; stride = 512; off = 0;   }
        else if (m < 9) { src = updW  + (size_t)(m - 6) * 131072; stride = 512; off = 0;   }
        else            { src = updW  + (size_t)(m - 9) * 131072; stride = 512; off = 256; }
        float* dst = WtB + (size_t)m * 65536;
        #pragma unroll
        for (int it = 0; it < 2; ++it) {
            const int j = it * 512 + tid, row = j >> 4, q = (j & 15) * 4;
            const float4 v = *(const float4*)(src + (size_t)(tr * 64 + row) * stride + off + tc * 64 + q);
            Tl[row][q + 0] = v.x; Tl[row][q + 1] = v.y;
            Tl[row][q + 2] = v.z; Tl[row][q + 3] = v.w;
        }
        __syncthreads();
        #pragma unroll
        for (int it = 0; it < 2; ++it) {
            const int j = it * 512 + tid, kgl = j >> 6, cl = j & 63;
            float4 v;
            v.x = Tl[cl][kgl * 4 + 0]; v.y = Tl[cl][kgl * 4 + 1];
            v.z = Tl[cl][kgl * 4 + 2]; v.w = Tl[cl][kgl * 4 + 3];
            *(float4*)(dst + (size_t)(tc * 16 + kgl) * 1024 + (tr * 64 + cl) * 4) = v;
        }
    }
    gridbar(1, flags, rel, bid, true);   // fence: publish WtB, kill poison

    float xu[8];                          // rq1: xU1 rows (persist over barrier)
    #pragma unroll
    for (int r = 0; r < 8; ++r) xu[r] = 0.f;
    float accU = 0.f;

    for (int i = 0; i < 3; ++i) {
        if (i > 0)
            accU = phaseB(i - 1, b, c, rq, part, WtB, updB, sc, aggl);

        // ---- build hid rows in LDS [row][k]
        if (i == 0) {
            #pragma unroll
            for (int r = 0; r < 4; ++r) {
                const int row = row0 + rq * 4 + r;
                hidl[(rq * 4 + r) * 256 + c] = feat[(size_t)row * 256 + c] * mask[row];
            }
        } else if (rq == 1) {
            #pragma unroll
            for (int r = 0; r < 8; ++r)
                hidl[r * 256 + c] = (xu[r] + accU) * mask[row0 + r];
        }
        __syncthreads();

        // ---- P1: x = hid @ aggW^T + aggB. rq groups SPLIT K (1x traffic),
        // depth-8 packed prefetch, v2f over k-pairs, 8 rows/thread.
        {
            const float4* Wq = (const float4*)(WtB + (size_t)i * 65536);
            const int kg0 = rq * 32;
            float4 buf[8];
            #pragma unroll
            for (int j = 0; j < 8; ++j) buf[j] = Wq[(size_t)(kg0 + j) * 256 + c];
            v2f acc[8];
            #pragma unroll
            for (int r = 0; r < 8; ++r) acc[r] = (v2f){0.f, 0.f};
            #pragma unroll
            for (int ph = 0; ph < 4; ++ph) {
                #pragma unroll
                for (int j = 0; j < 8; ++j) {
                    const float4 w = buf[j];
                    if (ph < 3) buf[j] = Wq[(size_t)(kg0 + (ph + 1) * 8 + j) * 256 + c];
                    const int kq = (kg0 + ph * 8 + j) * 4;
                    #pragma unroll
                    for (int r = 0; r < 8; ++r) {
                        const float4 h = *(const float4*)&hidl[r * 256 + kq];
                        acc[r] += (v2f){h.x, h.y} * (v2f){w.x, w.y};
                        acc[r] += (v2f){h.z, h.w} * (v2f){w.z, w.w};
                    }
                }
            }
            // reduce the two k-halves via LDS
            if (rq == 1) {
                #pragma unroll
                for (int r = 0; r < 8; ++r) sc[r * 256 + c] = acc[r].x + acc[r].y;
            }
            __syncthreads();
            if (rq == 0) {
                const float bb = aggB[i * 256 + c];
                #pragma unroll
                for (int r = 0; r < 8; ++r)
                    xl[r * 256 + c] = acc[r].x + acc[r].y + sc[r * 256 + c] + bb;
            }
            __syncthreads();
        }

        // ---- P2: rq0 streams W1 -> p ; rq1 streams U1 -> xU1 (1x traffic)
        float pr[8];
        {
            const float4* Sq = (const float4*)(WtB + (size_t)((rq ? 6 : 3) + i) * 65536);
            float4 buf[8];
            #pragma unroll
            for (int j = 0; j < 8; ++j) buf[j] = Sq[(size_t)j * 256 + c];
            v2f acc[8];
            #pragma unroll
            for (int r = 0; r < 8; ++r) acc[r] = (v2f){0.f, 0.f};
            #pragma unroll
            for (int ph = 0; ph < 8; ++ph) {
                #pragma unroll
                for (int j = 0; j < 8; ++j) {
                    const float4 w = buf[j];
                    if (ph < 7) buf[j] = Sq[(size_t)((ph + 1) * 8 + j) * 256 + c];
                    const int kq = (ph * 8 + j) * 4;
                    #pragma unroll
                    for (int r = 0; r < 8; ++r) {
                        const float4 xk = *(const float4*)&xl[r * 256 + kq];
                        acc[r] += (v2f){xk.x, xk.y} * (v2f){w.x, w.y};
                        acc[r] += (v2f){xk.z, xk.w} * (v2f){w.z, w.w};
                    }
                }
            }
            #pragma unroll
            for (int r = 0; r < 8; ++r) pr[r] = acc[r].x + acc[r].y;
        }
        if (rq == 1) {
            #pragma unroll
            for (int r = 0; r < 8; ++r) xu[r] = pr[r];
        } else {
            // ---- online-softmax partial over this block's 8 rows
            float m8 = pr[0];
            #pragma unroll
            for (int r = 1; r < 8; ++r) m8 = fmaxf(m8, pr[r]);
            float d8 = 0.f, n8 = 0.f;
            #pragma unroll
            for (int r = 0; r < 8; ++r) {
                const float e = __expf(pr[r] - m8);
                d8 += e;
                n8 += e * xl[r * 256 + c];
            }
            float* pb = part + (size_t)((i & 1) * 256 + bid) * 768;
            AG_ST(pb + c, m8);
            AG_ST(pb + 256 + c, d8);
            AG_ST(pb + 512 + c, n8);
        }
        gridbar(i + 2, flags, rel, bid, false);   // no fence: L2 stays warm
    }

    // ---- final combine + epilogue: out = xU1 + accU (rq1 holds xU1)
    accU = phaseB(2, b, c, rq, part, WtB, updB, sc, aggl);
    if (rq == 1) {
        #pragma unroll
        for (int r = 0; r < 8; ++r)
            out[(size_t)(row0 + r) * 256 + c] = xu[r] + accU;
    }
}

extern "C" void kernel_launch(void* const* d_in, const int* in_sizes, int n_in,
                              void* d_out, int out_size, void* d_ws, size_t ws_size,
                              hipStream_t stream) {
    const float* feat  = (const float*)d_in[0];
    const float* mask  = (const float*)d_in[1];
    const float* aggW  = (const float*)d_in[2];
    const float* aggB  = (const float*)d_in[3];
    const float* attnW = (const float*)d_in[4];
    // d_in[5] = attnB: cancels in softmax (constant along the s axis)
    const float* updW  = (const float*)d_in[6];
    const float* updB  = (const float*)d_in[7];

    float* WtB  = (float*)d_ws;                        // 12 * 65536 floats
    float* part = WtB + 12 * 65536;                    // 2 * 256 * 768 floats
    unsigned* flags = (unsigned*)(part + 2 * 256 * 768);
    unsigned* rel   = flags + NBLK * FPAD;

    fused_k<<<NBLK, 512, 0, stream>>>(
        feat, mask, aggW, aggB, attnW, updW, updB,
        WtB, part, flags, rel, (float*)d_out);
}